// Round 3
// baseline (313.934 us; speedup 1.0000x reference)
//
#include <hip/hip_runtime.h>
#include <hip/hip_bf16.h>
#include <cstddef>
#include <cstdint>

// StyleGAN2 SynthesisLayer fused: modulated transposed-conv (stride2 3x3) + FIR + noise/bias/lrelu
// Round 3: A(weights) streamed from global in MFMA-frag layout (no LDS), x double-buffered via
// global_load_lds with single barrier per K-chunk (2-phase pipeline), paired-dword vertical FIR.

typedef __attribute__((ext_vector_type(8))) short s16x8;
typedef __attribute__((ext_vector_type(4))) short s16x4;
typedef __attribute__((ext_vector_type(4))) float f32x4;

static __device__ __forceinline__ unsigned short f2bf(float v) {
  __hip_bfloat16 h = __float2bfloat16(v);
  return __builtin_bit_cast(unsigned short, h);
}
static __device__ __forceinline__ float bf2f(unsigned short u) {
  unsigned int x = ((unsigned int)u) << 16;
  return __builtin_bit_cast(float, x);
}

static __device__ __forceinline__ void gload16(const void* g, const void* l) {
  __builtin_amdgcn_global_load_lds((const __attribute__((address_space(1))) unsigned int*)g,
                                   (__attribute__((address_space(3))) unsigned int*)l, 16, 0, 0);
}

// ---------------- styles[b][ic] = w[b] . (aw[ic]*wg) + ab[ic] ----------------
__global__ void k_styles(const float* __restrict__ w, const float* __restrict__ aw,
                         const float* __restrict__ ab, float* __restrict__ styles) {
  int b = blockIdx.x;
  int ic = blockIdx.y * 32 + (threadIdx.x >> 3);
  int l = threadIdx.x & 7;
  const float wg = 0.044194173824159216f; // 1/sqrt(512)
  const float* wp = w + b * 512 + l * 64;
  const float* ap = aw + (size_t)ic * 512 + l * 64;
  float s = 0.f;
  for (int d = 0; d < 64; d += 4) {
    float4 wv = *(const float4*)(wp + d);
    float4 av = *(const float4*)(ap + d);
    s += wv.x * av.x + wv.y * av.y + wv.z * av.z + wv.w * av.w;
  }
  s += __shfl_down(s, 4, 64);
  s += __shfl_down(s, 2, 64);
  s += __shfl_down(s, 1, 64);
  if (l == 0) styles[b * 512 + ic] = s * wg + ab[ic];
}

// ------- per-oc: write wt2 (A-frag-coalesced bf16 layout) + dcoefs[b][oc] -------
// wt2 layout: [ocT16][kc16][tap9][mf2][lane64][8bf16]; lane=(l4*16+l15):
//   value = w[oc0+mf*16+l15][ic = kc*32 + l4*8 + e][tap]
__global__ void k_prep(const float* __restrict__ cw, const float* __restrict__ styles,
                       unsigned short* __restrict__ wt2, float* __restrict__ dcoefs,
                       int do_wt) {
  __shared__ float lw[4608];
  __shared__ float part[4][16];
  int oc = blockIdx.x, t = threadIdx.x;
  for (int k = t; k < 1152; k += 256)
    *(float4*)(lw + k * 4) = *(const float4*)(cw + (size_t)oc * 4608 + k * 4);
  __syncthreads();
  if (do_wt) {
    int ocT = oc >> 5, mf = (oc >> 4) & 1, l15 = oc & 15;
    for (int c = t; c < 576; c += 256) {
      int kc = c / 36, rem = c % 36, tap = rem >> 2, l4 = rem & 3;
      s16x8 v;
#pragma unroll
      for (int e = 0; e < 8; ++e) v[e] = (short)f2bf(lw[(kc * 32 + l4 * 8 + e) * 9 + tap]);
      *(s16x8*)(wt2 + ((size_t)(((ocT * 16 + kc) * 9 + tap) * 2 + mf) * 64 + l4 * 16 + l15) * 8) = v;
    }
  }
  float acc[16];
#pragma unroll
  for (int b2 = 0; b2 < 16; ++b2) acc[b2] = 0.f;
#pragma unroll
  for (int j = 0; j < 2; ++j) {
    int ic = t * 2 + j;
    float s2 = 0.f;
#pragma unroll
    for (int k = 0; k < 9; ++k) { float v = lw[ic * 9 + k]; s2 += v * v; }
#pragma unroll
    for (int b2 = 0; b2 < 16; ++b2) { float s = styles[b2 * 512 + ic]; acc[b2] += s2 * s * s; }
  }
#pragma unroll
  for (int off = 32; off > 0; off >>= 1) {
#pragma unroll
    for (int b2 = 0; b2 < 16; ++b2) acc[b2] += __shfl_down(acc[b2], off, 64);
  }
  int wid = t >> 6, lane = t & 63;
  if (lane == 0) {
    for (int b2 = 0; b2 < 16; ++b2) part[wid][b2] = acc[b2];
  }
  __syncthreads();
  if (t < 16) {
    float s = part[0][t] + part[1][t] + part[2][t] + part[3][t];
    dcoefs[t * 512 + oc] = rsqrtf(s + 1e-8f);
  }
}

// ------- padded modulated x: xtp[b][36][36][512] bf16, zero halo (pad 2 each side) -------
__global__ void k_xt(const float* __restrict__ x, const float* __restrict__ styles,
                     unsigned short* __restrict__ xtp) {
  __shared__ __align__(16) unsigned short trans[32][520];
  int pr = blockIdx.x, b = blockIdx.y, t = threadIdx.x;
  bool interior = (pr >= 2 && pr < 34);
  if (interior) {
    int iy = pr - 2;
    for (int task = t; task < 4096; task += 256) {  // 512 ic x 8 col-quads
      int ic = task >> 3, q = task & 7;
      float4 v = *(const float4*)(x + ((size_t)(b * 512 + ic)) * 1024 + iy * 32 + q * 4);
      float s = styles[b * 512 + ic];
      trans[q * 4 + 0][ic] = f2bf(v.x * s);
      trans[q * 4 + 1][ic] = f2bf(v.y * s);
      trans[q * 4 + 2][ic] = f2bf(v.z * s);
      trans[q * 4 + 3][ic] = f2bf(v.w * s);
    }
  }
  __syncthreads();
  for (int c = t; c < 2304; c += 256) {
    int pc = c >> 6, icc = c & 63;
    s16x8 v = {0, 0, 0, 0, 0, 0, 0, 0};
    if (interior && pc >= 2 && pc < 34) v = *(const s16x8*)&trans[pc - 2][icc * 8];
    *(s16x8*)(xtp + ((size_t)(b * 1296 + pr * 36 + pc)) * 512 + icc * 8) = v;
  }
}

// ---------------- main fused kernel ----------------
// LDS: two x-buffers [432 runs][80B] = 2 x 34560B = 69120B; epilogue y [16][19][68] bf16 aliased.
// x run = r*36 + c <-> (iy = J0-2+r, ix = c-2); A-frags direct from wt2 (global).
template <int PRE>
__global__ __launch_bounds__(256, 2)
void k_main(const unsigned short* __restrict__ xtp, const unsigned short* __restrict__ wt2,
            const float* __restrict__ xg, const float* __restrict__ cw,
            const float* __restrict__ styles, const float* __restrict__ dcoefs,
            const float* __restrict__ bias, const float* __restrict__ noise,
            float* __restrict__ out) {
  __shared__ __align__(16) unsigned char smem[69120];

  int bid = blockIdx.x;
  int q8 = (bid >> 3) + (bid & 7) * 128;  // XCD-contiguous remap (1024 = 8*128)
  const int ocT = q8 & 15, yT = (q8 >> 4) & 3, b = q8 >> 6;
  const int oc0 = ocT * 32;
  const int J0 = yT * 8, Y0 = yT * 16;
  const int tid = threadIdx.x, wid = tid >> 6, lane = tid & 63;
  const int l15 = lane & 15, l4 = lane >> 4;

  // frag geometry: py0 grid 9x34 (306 pos, 20 frags, 5/wave); py1 grid 10x34 (340 pos, 22 frags)
  const int fs1 = (wid < 2) ? wid * 6 : 12 + (wid - 2) * 5;
  const int NF1 = (wid < 2) ? 6 : 5;
  int bb0[5], bb1[6];
#pragma unroll
  for (int f = 0; f < 5; ++f) {
    int n = (wid * 5 + f) * 16 + l15;
    int jy = n / 34, jx = n - jy * 34;
    bb0[f] = ((jy + 1) * 36 + jx + 1) * 80 + l4 * 16;
  }
#pragma unroll
  for (int f = 0; f < 6; ++f) {
    int n = (fs1 + f) * 16 + l15;
    int jy = n / 34, jx = n - jy * 34;
    bb1[f] = ((jy + 1) * 36 + jx + 1) * 80 + l4 * 16;
  }

  f32x4 acc0[2][2][5];  // [px][mf][f]
  f32x4 acc1[2][2][6];
#pragma unroll
  for (int px = 0; px < 2; ++px)
#pragma unroll
    for (int mf = 0; mf < 2; ++mf) {
#pragma unroll
      for (int f = 0; f < 5; ++f) acc0[px][mf][f] = (f32x4){0.f, 0.f, 0.f, 0.f};
#pragma unroll
      for (int f = 0; f < 6; ++f) acc1[px][mf][f] = (f32x4){0.f, 0.f, 0.f, 0.f};
    }

  const unsigned short* xsb = xtp + ((size_t)(b * 1296 + J0 * 36)) * 512;

  // prologue: stage x chunk 0 into buf0
  if (PRE) {
    for (int i = wid; i < 34; i += 4) {
      int q = i * 64 + lane;
      int q2 = q < 2159 ? q : 2159;
      int run = q2 / 5;
      int c = q2 - run * 5; c = c > 3 ? 3 : c;
      gload16(xsb + run * 512 + c * 8, smem + i * 1024);
    }
    __syncthreads();
  }

  for (int kc = 0; kc < 16; ++kc) {
    const int ic0 = kc * 32;
    if (PRE) {
      if (kc < 15) {  // issue prefetch of next chunk into other buffer (drained by end barrier)
        char* dst = (char*)smem + ((kc + 1) & 1) * 34560;
        const unsigned short* src = xsb + (kc + 1) * 32;
        for (int i = wid; i < 34; i += 4) {
          int q = i * 64 + lane;
          int q2 = q < 2159 ? q : 2159;
          int run = q2 / 5;
          int c = q2 - run * 5; c = c > 3 ? 3 : c;
          gload16(src + run * 512 + c * 8, dst + i * 1024);
        }
      }
    } else {
      __syncthreads();  // prior reads done before overwriting single buffer
      for (int s = tid; s < 1728; s += 256) {
        int run = s >> 2, c = s & 3;
        int r = run / 36, cc = run - r * 36;
        int iy = J0 + r - 2, ix = cc - 2;
        s16x8 v = {0, 0, 0, 0, 0, 0, 0, 0};
        if ((unsigned)iy < 32u && (unsigned)ix < 32u) {
#pragma unroll
          for (int e = 0; e < 8; ++e) {
            int ic = ic0 + c * 8 + e;
            v[e] = (short)f2bf(xg[((size_t)(b * 512 + ic)) * 1024 + iy * 32 + ix] * styles[b * 512 + ic]);
          }
        }
        *(s16x8*)((char*)smem + run * 80 + c * 16) = v;
      }
      __syncthreads();
    }

    const char* BUF = (const char*)smem + (PRE ? (kc & 1) * 34560 : 0);
    const unsigned short* aB = wt2 + ((size_t)(ocT * 16 + kc)) * 9 * 1024 + lane * 8;

    // A-frag fetch helper (PRE: coalesced global; else: strided gather from cw)
#define LOAD_A(A, TAP0)                                                                   \
    {                                                                                     \
      if (PRE) {                                                                          \
        _Pragma("unroll") for (int kx = 0; kx < 3; ++kx)                                  \
          _Pragma("unroll") for (int mf = 0; mf < 2; ++mf)                                \
            A[kx][mf] = *(const s16x8*)(aB + ((TAP0 + kx) * 2 + mf) * 512);               \
      } else {                                                                            \
        _Pragma("unroll") for (int kx = 0; kx < 3; ++kx)                                  \
          _Pragma("unroll") for (int mf = 0; mf < 2; ++mf) {                              \
            _Pragma("unroll") for (int e = 0; e < 8; ++e)                                 \
              A[kx][mf][e] = (short)f2bf(                                                 \
                  cw[((size_t)(oc0 + mf * 16 + l15) * 512 + ic0 + l4 * 8 + e) * 9 + TAP0 + kx]); \
          }                                                                               \
      }                                                                                   \
    }

    {  // py0, ky=0 (taps 0..2): B rows jy+2 -> +2880/+2960
      s16x8 A[3][2];
      LOAD_A(A, 0)
#pragma unroll
      for (int f = 0; f < 5; ++f) {
        const char* bp = BUF + bb0[f];
        s16x8 B3 = *(const s16x8*)(bp + 2880);
        s16x8 B4 = *(const s16x8*)(bp + 2960);
#pragma unroll
        for (int mf = 0; mf < 2; ++mf) {
          acc0[0][mf][f] = __builtin_amdgcn_mfma_f32_16x16x32_bf16(A[0][mf], B4, acc0[0][mf][f], 0, 0, 0);
          acc0[0][mf][f] = __builtin_amdgcn_mfma_f32_16x16x32_bf16(A[2][mf], B3, acc0[0][mf][f], 0, 0, 0);
          acc0[1][mf][f] = __builtin_amdgcn_mfma_f32_16x16x32_bf16(A[1][mf], B3, acc0[1][mf][f], 0, 0, 0);
        }
      }
    }
    {  // py0, ky=2 (taps 6..8): B rows jy+1 -> +0/+80
      s16x8 A[3][2];
      LOAD_A(A, 6)
#pragma unroll
      for (int f = 0; f < 5; ++f) {
        const char* bp = BUF + bb0[f];
        s16x8 B1 = *(const s16x8*)(bp);
        s16x8 B2 = *(const s16x8*)(bp + 80);
#pragma unroll
        for (int mf = 0; mf < 2; ++mf) {
          acc0[0][mf][f] = __builtin_amdgcn_mfma_f32_16x16x32_bf16(A[0][mf], B2, acc0[0][mf][f], 0, 0, 0);
          acc0[0][mf][f] = __builtin_amdgcn_mfma_f32_16x16x32_bf16(A[2][mf], B1, acc0[0][mf][f], 0, 0, 0);
          acc0[1][mf][f] = __builtin_amdgcn_mfma_f32_16x16x32_bf16(A[1][mf], B1, acc0[1][mf][f], 0, 0, 0);
        }
      }
    }
    {  // py1, ky=1 (taps 3..5): B rows jy+1 -> +0/+80
      s16x8 A[3][2];
      LOAD_A(A, 3)
#pragma unroll
      for (int f = 0; f < 6; ++f) {
        if (f < NF1) {
          const char* bp = BUF + bb1[f];
          s16x8 B1 = *(const s16x8*)(bp);
          s16x8 B2 = *(const s16x8*)(bp + 80);
#pragma unroll
          for (int mf = 0; mf < 2; ++mf) {
            acc1[0][mf][f] = __builtin_amdgcn_mfma_f32_16x16x32_bf16(A[0][mf], B2, acc1[0][mf][f], 0, 0, 0);
            acc1[0][mf][f] = __builtin_amdgcn_mfma_f32_16x16x32_bf16(A[2][mf], B1, acc1[0][mf][f], 0, 0, 0);
            acc1[1][mf][f] = __builtin_amdgcn_mfma_f32_16x16x32_bf16(A[1][mf], B1, acc1[1][mf][f], 0, 0, 0);
          }
        }
      }
    }
#undef LOAD_A
    if (PRE) __syncthreads();  // implicit vmcnt(0): drains next-chunk prefetch
  }

  // ---- epilogue: per oc-half: dump y (bf16) -> vertical FIR -> horizontal FIR + store ----
  unsigned short* ly = (unsigned short*)smem;  // [16][19][68]
#pragma unroll
  for (int mf = 0; mf < 2; ++mf) {
    __syncthreads();
#pragma unroll
    for (int f = 0; f < 5; ++f) {
      int n = (wid * 5 + f) * 16 + l15;
      if (n < 306) {
        int jy = n / 34, jx = n - jy * 34;
        int yr = 2 * jy + 1;
#pragma unroll
        for (int px = 0; px < 2; ++px) {
          int yc = 2 * jx + 1 - px;
#pragma unroll
          for (int r = 0; r < 4; ++r)
            ly[(l4 * 4 + r) * 1292 + yr * 68 + yc] = f2bf(acc0[px][mf][f][r]);
        }
      }
    }
#pragma unroll
    for (int f = 0; f < 6; ++f) {
      if (f < NF1) {
        int n = (fs1 + f) * 16 + l15;
        if (n < 340) {
          int jy = n / 34, jx = n - jy * 34;
          int yr = 2 * jy;
#pragma unroll
          for (int px = 0; px < 2; ++px) {
            int yc = 2 * jx + 1 - px;
#pragma unroll
            for (int r = 0; r < 4; ++r)
              ly[(l4 * 4 + r) * 1292 + yr * 68 + yc] = f2bf(acc1[px][mf][f][r]);
          }
        }
      }
    }
    __syncthreads();
    // vertical FIR on column PAIRS (dword-wide LDS ops, conflict-free)
    for (int task = tid; task < 544; task += 256) {
      int ocr = task / 34, cp = task - ocr * 34;
      unsigned int* colp = (unsigned int*)(ly + ocr * 1292) + cp;
      unsigned int u0 = colp[0], u1 = colp[34], u2 = colp[68];
#pragma unroll
      for (int Y = 0; Y < 16; ++Y) {
        unsigned int u3 = colp[(Y + 3) * 34];
        float a0 = bf2f((unsigned short)(u0 & 0xffff)), b0 = bf2f((unsigned short)(u0 >> 16));
        float a1 = bf2f((unsigned short)(u1 & 0xffff)), b1 = bf2f((unsigned short)(u1 >> 16));
        float a2 = bf2f((unsigned short)(u2 & 0xffff)), b2 = bf2f((unsigned short)(u2 >> 16));
        float a3 = bf2f((unsigned short)(u3 & 0xffff)), b3 = bf2f((unsigned short)(u3 >> 16));
        float va = 0.25f * (a0 + a3) + 0.75f * (a1 + a2);
        float vb = 0.25f * (b0 + b3) + 0.75f * (b1 + b2);
        colp[Y * 34] = (unsigned int)f2bf(va) | ((unsigned int)f2bf(vb) << 16);
        u0 = u1; u1 = u2; u2 = u3;
      }
    }
    __syncthreads();
    for (int task = tid; task < 1024; task += 256) {
      int ocr = task >> 6, rem = task & 63;
      int Y = rem >> 2, qq = rem & 3;
      const unsigned short* rowp = ly + ocr * 1292 + Y * 68 + qq * 16;
      float vb[20];
#pragma unroll
      for (int k = 0; k < 5; ++k) {
        s16x4 ch = *(const s16x4*)(rowp + k * 4);
#pragma unroll
        for (int j2 = 0; j2 < 4; ++j2) vb[k * 4 + j2] = bf2f((unsigned short)ch[j2]);
      }
      int oc = oc0 + mf * 16 + ocr;
      int Yg = Y0 + Y, Xg = qq * 16;
      float dc = dcoefs[b * 512 + oc];
      float bv = bias[oc];
      const float* np = noise + Yg * 64 + Xg;
      float* op = out + (((size_t)(b * 512 + oc)) * 64 + Yg) * 64 + Xg;
#pragma unroll
      for (int xx = 0; xx < 16; ++xx) {
        float o = 0.25f * (vb[xx] + vb[xx + 3]) + 0.75f * (vb[xx + 1] + vb[xx + 2]);
        o = o * dc + np[xx] + bv;
        o = (o > 0.f ? o : 0.2f * o) * 1.4142135623730951f;
        op[xx] = o;
      }
    }
  }
}

extern "C" void kernel_launch(void* const* d_in, const int* in_sizes, int n_in,
                              void* d_out, int out_size, void* d_ws, size_t ws_size,
                              hipStream_t stream) {
  const float* x = (const float*)d_in[0];      // [16,512,32,32]
  const float* w = (const float*)d_in[1];      // [16,512]
  const float* aw = (const float*)d_in[2];     // [512,512]
  const float* ab = (const float*)d_in[3];     // [512]
  const float* cw = (const float*)d_in[4];     // [512,512,3,3]
  const float* bias = (const float*)d_in[5];   // [512]
  const float* noise = (const float*)d_in[6];  // [64,64]
  float* out = (float*)d_out;

  float* styles = (float*)d_ws;                                   // 8192 f32
  float* dcoefs = styles + 8192;                                  // 8192 f32
  unsigned short* xtp = (unsigned short*)((char*)d_ws + 65536);   // 16*1296*512 bf16
  unsigned short* wt2 = xtp + (size_t)16 * 1296 * 512;            // 16*16*9*2*64*8 bf16
  size_t need = 65536 + (size_t)16 * 1296 * 512 * 2 + (size_t)16 * 16 * 9 * 1024 * 2;
  int pre = (ws_size >= need) ? 1 : 0;

  k_styles<<<dim3(16, 16), 256, 0, stream>>>(w, aw, ab, styles);
  k_prep<<<dim3(512), 256, 0, stream>>>(cw, styles, wt2, dcoefs, pre);
  if (pre) {
    k_xt<<<dim3(36, 16), 256, 0, stream>>>(x, styles, xtp);
    k_main<1><<<dim3(1024), 256, 0, stream>>>(xtp, wt2, x, cw, styles, dcoefs, bias, noise, out);
  } else {
    k_main<0><<<dim3(1024), 256, 0, stream>>>(xtp, wt2, x, cw, styles, dcoefs, bias, noise, out);
  }
}